// Round 11
// baseline (487.487 us; speedup 1.0000x reference)
//
#include <hip/hip_runtime.h>
#include <hip/hip_bf16.h>
#include <math.h>

#define T_TOK 16384
#define DMODEL 1024
#define HID 512
#define NEXP 16
#define NASSIGN (T_TOK * 2)             // total (token, expert) pairs
#define HIST_BLK 64                     // blocks in hist/scatter phase
#define TOK_PER_BLK (T_TOK / HIST_BLK)  // 256
#define NMB_MAX 143                     // max total m-blocks: 128 + 15 (rounding)

typedef __bf16 bf16_8 __attribute__((ext_vector_type(8)));
typedef __bf16 bf16_4 __attribute__((ext_vector_type(4)));
typedef float f32_4 __attribute__((ext_vector_type(4)));

// Async global->LDS, 16B per lane. HW dest = wave-uniform base + lane*16 (linear).
__device__ __forceinline__ void gload16(const __bf16* g, __bf16* l) {
  __builtin_amdgcn_global_load_lds(
      (const __attribute__((address_space(1))) void*)g,
      (__attribute__((address_space(3))) void*)l, 16, 0, 0);
}

// ---------------- gate compute v2: gw cached in LDS, 4-token batching, no atomics -------------
__global__ __launch_bounds__(256) void gate_compute_kernel(
    const float* __restrict__ x, const float* __restrict__ gw, const float* __restrict__ gb,
    __bf16* __restrict__ xb, int* __restrict__ topk_idx, float2* __restrict__ topk_w)
{
  __shared__ __align__(16) float gws[4 * 1024 * 4];   // 64 KB: [g][k] f32_4

  int tid = threadIdx.x;
#pragma unroll
  for (int i = 0; i < 16; ++i) {
    int c = i * 256 + tid;
    f32_4 v = ((const f32_4*)gw)[c];
    ((f32_4*)gws)[((c & 3) << 10) | (c >> 2)] = v;
  }
  __syncthreads();

  int wave = tid >> 6, lane = tid & 63;
  int tbase = blockIdx.x * 32 + wave * 8;

#pragma unroll 1
  for (int pass = 0; pass < 2; ++pass) {
    int t0 = tbase + pass * 4;
    const float* xr0 = x + (size_t)t0 * DMODEL;
    const float* xr1 = xr0 + DMODEL;
    const float* xr2 = xr1 + DMODEL;
    const float* xr3 = xr2 + DMODEL;
    __bf16* xw0 = xb + (size_t)t0 * DMODEL;
    __bf16* xw1 = xw0 + DMODEL;
    __bf16* xw2 = xw1 + DMODEL;
    __bf16* xw3 = xw2 + DMODEL;

    f32_4 acc0[4], acc1[4], acc2[4], acc3[4];
    {
      f32_4 z = {0.f, 0.f, 0.f, 0.f};
#pragma unroll
      for (int g = 0; g < 4; ++g) { acc0[g] = z; acc1[g] = z; acc2[g] = z; acc3[g] = z; }
    }

#pragma unroll
    for (int j = 0; j < 16; ++j) {
      int k = j * 64 + lane;
      float xv0 = xr0[k], xv1 = xr1[k], xv2 = xr2[k], xv3 = xr3[k];
      xw0[k] = (__bf16)xv0;
      xw1[k] = (__bf16)xv1;
      xw2[k] = (__bf16)xv2;
      xw3[k] = (__bf16)xv3;
      f32_4 w0 = ((const f32_4*)gws)[k];
      f32_4 w1 = ((const f32_4*)gws)[1024 + k];
      f32_4 w2 = ((const f32_4*)gws)[2048 + k];
      f32_4 w3 = ((const f32_4*)gws)[3072 + k];
      acc0[0] += xv0 * w0; acc0[1] += xv0 * w1; acc0[2] += xv0 * w2; acc0[3] += xv0 * w3;
      acc1[0] += xv1 * w0; acc1[1] += xv1 * w1; acc1[2] += xv1 * w2; acc1[3] += xv1 * w3;
      acc2[0] += xv2 * w0; acc2[1] += xv2 * w1; acc2[2] += xv2 * w2; acc2[3] += xv2 * w3;
      acc3[0] += xv3 * w0; acc3[1] += xv3 * w1; acc3[2] += xv3 * w2; acc3[3] += xv3 * w3;
    }

#pragma unroll
    for (int g = 0; g < 4; ++g)
#pragma unroll
      for (int w = 0; w < 4; ++w) {
        float v0 = acc0[g][w], v1 = acc1[g][w], v2 = acc2[g][w], v3 = acc3[g][w];
#pragma unroll
        for (int s = 32; s; s >>= 1) {
          v0 += __shfl_xor(v0, s, 64);
          v1 += __shfl_xor(v1, s, 64);
          v2 += __shfl_xor(v2, s, 64);
          v3 += __shfl_xor(v3, s, 64);
        }
        acc0[g][w] = v0; acc1[g][w] = v1; acc2[g][w] = v2; acc3[g][w] = v3;
      }

    int ti = lane & 3;
    float sc[16];
#pragma unroll
    for (int e = 0; e < 16; ++e) {
      int g = e >> 2, w = e & 3;
      float v = ti == 0 ? acc0[g][w] : ti == 1 ? acc1[g][w] : ti == 2 ? acc2[g][w] : acc3[g][w];
      sc[e] = v + gb[e];
    }
    float mx = -1e30f;
#pragma unroll
    for (int e = 0; e < 16; ++e) mx = fmaxf(mx, sc[e]);
    float Z = 0.f;
#pragma unroll
    for (int e = 0; e < 16; ++e) { sc[e] = expf(sc[e] - mx); Z += sc[e]; }
    int i0 = 0; float s0 = sc[0];
#pragma unroll
    for (int e = 1; e < 16; ++e) if (sc[e] > s0) { s0 = sc[e]; i0 = e; }
    int i1 = -1; float s1 = -1e30f;
#pragma unroll
    for (int e = 0; e < 16; ++e) if (e != i0 && sc[e] > s1) { s1 = sc[e]; i1 = e; }
    s0 /= Z; s1 /= Z;
    float dn = s0 + s1 + 1e-9f;
    if (lane < 4) {
      int t = t0 + ti;
      topk_idx[t] = i0 | (i1 << 8);
      topk_w[t] = make_float2(s0 / dn, s1 / dn);
    }
  }
}

// ---------------- per-block expert histogram (LDS atomics only) ----------------
__global__ __launch_bounds__(256) void hist_kernel(
    const int* __restrict__ topk_idx, int* __restrict__ block_hist)
{
  __shared__ int cnt[NEXP];
  int tid = threadIdx.x;
  if (tid < NEXP) cnt[tid] = 0;
  __syncthreads();
  int t = blockIdx.x * TOK_PER_BLK + tid;
  int p = topk_idx[t];
  atomicAdd(&cnt[p & 0xff], 1);
  atomicAdd(&cnt[p >> 8], 1);
  __syncthreads();
  if (tid < NEXP) block_hist[blockIdx.x * NEXP + tid] = cnt[tid];
}

// ---------------- scan: counts, offsets, block bases, aux loss, m-block map ----------------
__global__ void scan2_kernel(const int* __restrict__ block_hist,
                             int* __restrict__ counts, int* __restrict__ offsets,
                             int* __restrict__ block_base, int* __restrict__ mb_tab,
                             int* __restrict__ nmb, float* __restrict__ aux_out)
{
  __shared__ int cl[NEXP];
  int lane = threadIdx.x;
  if (lane < NEXP) {
    int s = 0;
    for (int b = 0; b < HIST_BLK; ++b) s += block_hist[b * NEXP + lane];
    cl[lane] = s;
    counts[lane] = s;
  }
  __syncthreads();
  if (lane < NEXP) {
    int off = 0;
    for (int e = 0; e < lane; ++e) off += cl[e];
    offsets[lane] = off;
    int base = off;
    for (int b = 0; b < HIST_BLK; ++b) {
      block_base[b * NEXP + lane] = base;
      base += block_hist[b * NEXP + lane];
    }
  }
  if (lane == 0) {
    int tot = 0; float pen = 0.f;
    const float cap = 1.25f * (float)(T_TOK * 2) / (float)NEXP; // 2560
    for (int e = 0; e < NEXP; ++e) {
      tot += cl[e];
      float ld = (float)cl[e] - cap;
      pen += ld > 0.f ? ld : 0.f;
    }
    offsets[NEXP] = tot;
    aux_out[0] = 0.01f * pen / (float)NEXP / (float)T_TOK;
    // m-block map: flat list of (expert<<8 | mblock) for all non-empty tiles
    int idx = 0;
    for (int e = 0; e < NEXP; ++e) {
      int nb = (cl[e] + 255) >> 8;
      for (int b = 0; b < nb; ++b) mb_tab[idx++] = (e << 8) | b;
    }
    nmb[0] = idx;
  }
}

// ---------------- scatter: compact-list positions + inverse map (token -> slots) ----------------
__global__ __launch_bounds__(256) void scatter_kernel(
    const int* __restrict__ topk_idx, const int* __restrict__ block_base,
    int* __restrict__ tok_list, int2* __restrict__ tok_slots)
{
  __shared__ int base[NEXP];
  int tid = threadIdx.x;
  if (tid < NEXP) base[tid] = block_base[blockIdx.x * NEXP + tid];
  __syncthreads();
  int t = blockIdx.x * TOK_PER_BLK + tid;
  int p = topk_idx[t];
  int i0 = p & 0xff, i1 = p >> 8;
  int p0 = atomicAdd(&base[i0], 1);
  tok_list[p0] = t;
  int p1 = atomicAdd(&base[i1], 1);
  tok_list[p1] = t;
  tok_slots[t] = make_int2(p0, p1);
}

// ---------------- transpose gp/up fp32[E][1024][512] -> interleaved bf16 wb1[E][n'][1024]
__global__ __launch_bounds__(256) void transpose_w1_kernel(const float* __restrict__ gp,
                                                           const float* __restrict__ up,
                                                           __bf16* __restrict__ wb1)
{
  __shared__ float tile[32][33];
  int ez = blockIdx.z;
  int e = ez >> 1, isup = ez & 1;
  const float* in = isup ? up : gp;
  int c0 = blockIdx.x * 32, r0 = blockIdx.y * 32;
  const float* src = in + ((size_t)e * 1024 + r0) * 512 + c0;
#pragma unroll
  for (int i = 0; i < 4; ++i) {
    int r = threadIdx.y + i * 8;
    tile[r][threadIdx.x] = src[(size_t)r * 512 + threadIdx.x];
  }
  __syncthreads();
#pragma unroll
  for (int i = 0; i < 4; ++i) {
    int cc = threadIdx.y + i * 8;
    int np = 2 * c0 + 2 * (cc & ~15) + (cc & 15) + 16 * isup;
    wb1[((size_t)e * 1024 + np) * 1024 + r0 + threadIdx.x] = (__bf16)tile[threadIdx.x][cc];
  }
}

// ---------------- transpose dp fp32[E][512][1024] -> bf16 dpb[E][1024][512] ----------------
__global__ __launch_bounds__(256) void transpose_dp_kernel(const float* __restrict__ in,
                                                           __bf16* __restrict__ out)
{
  __shared__ float tile[32][33];
  int e = blockIdx.z;
  int c0 = blockIdx.x * 32, r0 = blockIdx.y * 32;
  const float* src = in + ((size_t)e * 512 + r0) * 1024 + c0;
#pragma unroll
  for (int i = 0; i < 4; ++i) {
    int r = threadIdx.y + i * 8;
    tile[r][threadIdx.x] = src[(size_t)r * 1024 + threadIdx.x];
  }
  __syncthreads();
  __bf16* dst = out + ((size_t)e * 1024 + c0) * 512 + r0;
#pragma unroll
  for (int i = 0; i < 4; ++i) {
    int c = threadIdx.y + i * 8;
    dst[(size_t)c * 512 + threadIdx.x] = (__bf16)tile[threadIdx.x][c];
  }
}

// ==================== 8-wave 256x256xBK32 grouped-GEMM, 64 KB LDS, 2 blocks/CU ===============
// R10 post-mortem: depth-4 pipeline at K=32 tiles wastes ~19% in prologue/epilogue (negative);
// BK32 swizzle chunk^=(l16&3) was a 4-way bank conflict (6.6M measured). This version:
// - depth-2 double-buffer (64 KB LDS + 1 KB toks) -> TWO blocks/CU; barrier/drain bubbles of
//   one block hide under the other block's MFMA (m114 co-residency overlap) instead of deep
//   in-block pipelining.
// - CORRECTED swizzle: slot = quad ^ ((l16>>1)&3). bank-start = (l16&1)*16 + 4*(quad^((l16>>1)&3))
//   -> 8 distinct banks x 2 lanes = 2-way = free (m136). Store side f(r)=(r>>1)&3 matches
//   (row bases of frag reads are 16-aligned; ga1's +128 row offset preserves f).
// - cadence per 32-K tile: 2 phases x 16 MFMA, 12 ds_read_b128, 4 gloads, 4 barriers
//   (same per-K density as the proven R6 schedule); per-tile vmcnt(0) drain (depth-2).
// - keeps R10's proven-good block-map grid (572 blocks) + T1 bijective XCD swizzle
//   (FETCH_SIZE 146->70 MB measured).

#define PHASE_MID()                                          \
  __builtin_amdgcn_sched_barrier(0);                         \
  __builtin_amdgcn_s_barrier();                              \
  asm volatile("s_waitcnt lgkmcnt(0)" ::: "memory");         \
  __builtin_amdgcn_sched_barrier(0);                         \
  __builtin_amdgcn_s_setprio(1);

#define PHASE_END()                                          \
  __builtin_amdgcn_s_setprio(0);                             \
  __builtin_amdgcn_sched_barrier(0);                         \
  __builtin_amdgcn_s_barrier();

#define MF(mi, ni, a, b) acc[mi][ni] = __builtin_amdgcn_mfma_f32_16x16x32_bf16(a, b, acc[mi][ni], 0, 0, 0)

#define STAGE_A(b, kt) {                                          \
    gload16(ga0 + (kt) * 32, lds + (b) * 16384 + tid * 8);        \
    gload16(ga1 + (kt) * 32, lds + (b) * 16384 + 4096 + tid * 8); }
#define STAGE_B(b, kt) {                                          \
    gload16(gb0 + (kt) * 32, lds + (b) * 16384 + 8192 + tid * 8); \
    gload16(gb1 + (kt) * 32, lds + (b) * 16384 + 12288 + tid * 8); }

#define GTILE(ktv, STG)                                                           \
  {                                                                               \
    const __bf16* A_ = lds + ((ktv) & 1) * 16384;                                 \
    const __bf16* B_ = A_ + 8192;                                                 \
    bf16_8 af0, af1, af2, af3, bf0, bf1, bf2, bf3;                                \
    af0 = *(const bf16_8*)(A_ + abase + 0 * 512 + sq);                            \
    af1 = *(const bf16_8*)(A_ + abase + 1 * 512 + sq);                            \
    af2 = *(const bf16_8*)(A_ + abase + 2 * 512 + sq);                            \
    af3 = *(const bf16_8*)(A_ + abase + 3 * 512 + sq);                            \
    bf0 = *(const bf16_8*)(B_ + bbase + 0 * 512 + sq);                            \
    bf1 = *(const bf16_8*)(B_ + bbase + 1 * 512 + sq);                            \
    bf2 = *(const bf16_8*)(B_ + bbase + 2 * 512 + sq);                            \
    bf3 = *(const bf16_8*)(B_ + bbase + 3 * 512 + sq);                            \
    if (STG) STAGE_A(((ktv) + 1) & 1, (ktv) + 1);                                 \
    PHASE_MID();                                                                  \
    MF(0, 0, af0, bf0); MF(0, 1, af0, bf1); MF(0, 2, af0, bf2); MF(0, 3, af0, bf3); \
    MF(1, 0, af1, bf0); MF(1, 1, af1, bf1); MF(1, 2, af1, bf2); MF(1, 3, af1, bf3); \
    MF(2, 0, af2, bf0); MF(2, 1, af2, bf1); MF(2, 2, af2, bf2); MF(2, 3, af2, bf3); \
    MF(3, 0, af3, bf0); MF(3, 1, af3, bf1); MF(3, 2, af3, bf2); MF(3, 3, af3, bf3); \
    PHASE_END();                                                                  \
    af0 = *(const bf16_8*)(A_ + abase + 4 * 512 + sq);                            \
    af1 = *(const bf16_8*)(A_ + abase + 5 * 512 + sq);                            \
    af2 = *(const bf16_8*)(A_ + abase + 6 * 512 + sq);                            \
    af3 = *(const bf16_8*)(A_ + abase + 7 * 512 + sq);                            \
    if (STG) STAGE_B(((ktv) + 1) & 1, (ktv) + 1);                                 \
    PHASE_MID();                                                                  \
    MF(4, 0, af0, bf0); MF(4, 1, af0, bf1); MF(4, 2, af0, bf2); MF(4, 3, af0, bf3); \
    MF(5, 0, af1, bf0); MF(5, 1, af1, bf1); MF(5, 2, af1, bf2); MF(5, 3, af1, bf3); \
    MF(6, 0, af2, bf0); MF(6, 1, af2, bf1); MF(6, 2, af2, bf2); MF(6, 3, af2, bf3); \
    MF(7, 0, af3, bf0); MF(7, 1, af3, bf1); MF(7, 2, af3, bf2); MF(7, 3, af3, bf3); \
    __builtin_amdgcn_s_setprio(0);                                                \
    __builtin_amdgcn_sched_barrier(0);                                            \
    if (STG) { asm volatile("s_waitcnt vmcnt(0)" ::: "memory"); }                 \
    __builtin_amdgcn_sched_barrier(0);                                            \
    __builtin_amdgcn_s_barrier();                                                 \
  }

template<int KTILES>
__device__ __forceinline__ void gemm8w(
    const __bf16* ga0, const __bf16* ga1,   // A source (this thread's 2 row streams)
    const __bf16* gb0, const __bf16* gb1,   // B source
    __bf16* lds, f32_4 (&acc)[8][4])
{
  const int tid = threadIdx.x;
  const int wid = tid >> 6, wr = wid >> 2, wc = wid & 3;
  const int lane = tid & 63, quad = lane >> 4, l16 = lane & 15;
  const int sq = (quad ^ ((l16 >> 1) & 3)) * 8;  // swizzled slot offset (elements): 2-way max
  const int abase = (wr * 128 + l16) * 32;
  const int bbase = (wc * 64 + l16) * 32;

  // Prologue: stage tile 0, drain, barrier (1/KTILES waste).
  STAGE_A(0, 0); STAGE_B(0, 0);
  asm volatile("s_waitcnt vmcnt(0)" ::: "memory");
  __builtin_amdgcn_sched_barrier(0);
  __builtin_amdgcn_s_barrier();

#pragma unroll 1
  for (int kt = 0; kt < KTILES - 1; ++kt) {
    GTILE(kt, 1);
  }
  GTILE(KTILES - 1, 0);
}

// -------- FFN1: h = (x@gp + b) * silu(x@up + b), B = interleaved wb1, A gathered --------
__global__ __launch_bounds__(512, 2) void ffn1_kernel(
    const __bf16* __restrict__ xb, const __bf16* __restrict__ wb1,
    const float* __restrict__ gp_b, const float* __restrict__ up_b,
    const int* __restrict__ counts, const int* __restrict__ offsets,
    const int* __restrict__ tok_list, const int* __restrict__ mb_tab,
    const int* __restrict__ nmb, __bf16* __restrict__ h)
{
  __shared__ __align__(16) __bf16 lds[2 * 16384];   // 64 KB: 2 x (A 16KB + B 16KB)
  __shared__ int toks[256];

  // T1: bijective XCD swizzle over nwg = 4*143 = 572 (q=71, r=4).
  int lin = blockIdx.y * 4 + blockIdx.x;
  int xcd = lin & 7, sub = lin >> 3;
  int wg = (xcd < 4 ? xcd * 72 : 288 + (xcd - 4) * 71) + sub;
  int y = wg >> 2, xn = wg & 3;
  if (y >= nmb[0]) return;
  int me = mb_tab[y];
  int e = me >> 8;
  int m0 = (me & 255) << 8;
  int cnt = counts[e], offe = offsets[e];
  int n0 = xn * 256;   // n' base (interleaved g/u space)

  int tid = threadIdx.x;
  if (tid < 256) {
    int r = m0 + tid;
    toks[tid] = tok_list[offe + (r < cnt ? r : cnt - 1)];  // clamp: garbage rows never stored
  }
  __syncthreads();

  int rr = tid >> 2;                               // chunk row 0..127
  int ko = ((tid & 3) ^ ((rr >> 1) & 3)) * 8;      // swizzled source chunk (constant per thread)

  const __bf16* ga0 = xb + (size_t)toks[rr] * DMODEL + ko;
  const __bf16* ga1 = xb + (size_t)toks[128 + rr] * DMODEL + ko;
  const __bf16* gb0 = wb1 + ((size_t)e * 1024 + n0 + rr) * DMODEL + ko;
  const __bf16* gb1 = wb1 + ((size_t)e * 1024 + n0 + 128 + rr) * DMODEL + ko;

  f32_4 acc[8][4];
  {
    f32_4 z = {0.f, 0.f, 0.f, 0.f};
#pragma unroll
    for (int a = 0; a < 8; ++a)
#pragma unroll
      for (int b = 0; b < 4; ++b) acc[a][b] = z;
  }

  gemm8w<DMODEL / 32>(ga0, ga1, gb0, gb1, lds, acc);

  int wid = tid >> 6, wr = wid >> 2, wc = wid & 3;
  int lane = tid & 63, quad = lane >> 4, l16 = lane & 15;

  // Epilogue: pair n'-frags (2j, 2j+1) = (g, u); h col c = n0/2 + wc*32 + j*16 + l16.
#pragma unroll
  for (int mi = 0; mi < 8; ++mi)
#pragma unroll
    for (int j = 0; j < 2; ++j) {
      int c = (n0 >> 1) + wc * 32 + j * 16 + l16;
      float gbias = gp_b[e * HID + c];
      float ubias = up_b[e * HID + c];
#pragma unroll
      for (int rg = 0; rg < 4; ++rg) {
        int r = m0 + wr * 128 + mi * 16 + quad * 4 + rg;  // C/D: col=lane&15, row=quad*4+reg
        if (r < cnt) {
          float g = acc[mi][2 * j][rg] + gbias;
          float u = acc[mi][2 * j + 1][rg] + ubias;
          float sw = u / (1.f + expf(-u));
          h[(size_t)(offe + r) * HID + c] = (__bf16)(g * sw);
        }
      }
    }
}

// -------- FFN2: ybuf[slot] = h[slot] @ dp + b (contiguous A, coalesced stores, NO atomics) ----
__global__ __launch_bounds__(512, 2) void ffn2_kernel(
    const __bf16* __restrict__ h, const __bf16* __restrict__ dpb, const float* __restrict__ dp_b,
    const int* __restrict__ counts, const int* __restrict__ offsets,
    const int* __restrict__ mb_tab, const int* __restrict__ nmb,
    __bf16* __restrict__ ybuf)
{
  __shared__ __align__(16) __bf16 lds[2 * 16384];   // 64 KB

  int lin = blockIdx.y * 4 + blockIdx.x;
  int xcd = lin & 7, sub = lin >> 3;
  int wg = (xcd < 4 ? xcd * 72 : 288 + (xcd - 4) * 71) + sub;
  int y = wg >> 2, xn = wg & 3;
  if (y >= nmb[0]) return;
  int me = mb_tab[y];
  int e = me >> 8;
  int m0 = (me & 255) << 8;
  int cnt = counts[e], offe = offsets[e];
  int n0 = xn * 256;

  int tid = threadIdx.x;
  int rr = tid >> 2;
  int ko = ((tid & 3) ^ ((rr >> 1) & 3)) * 8;

  int ra0 = m0 + rr;        if (ra0 >= cnt) ra0 = cnt - 1;   // clamp: garbage rows never stored
  int ra1 = m0 + 128 + rr;  if (ra1 >= cnt) ra1 = cnt - 1;
  const __bf16* ga0 = h + (size_t)(offe + ra0) * HID + ko;
  const __bf16* ga1 = h + (size_t)(offe + ra1) * HID + ko;
  const __bf16* gb0 = dpb + ((size_t)e * DMODEL + n0 + rr) * HID + ko;
  const __bf16* gb1 = dpb + ((size_t)e * DMODEL + n0 + 128 + rr) * HID + ko;

  f32_4 acc[8][4];
  {
    f32_4 z = {0.f, 0.f, 0.f, 0.f};
#pragma unroll
    for (int a = 0; a < 8; ++a)
#pragma unroll
      for (int b = 0; b < 4; ++b) acc[a][b] = z;
  }

  gemm8w<HID / 32>(ga0, ga1, gb0, gb1, lds, acc);

  int wid = tid >> 6, wr = wid >> 2, wc = wid & 3;
  int lane = tid & 63, quad = lane >> 4, l16 = lane & 15;

#pragma unroll
  for (int mi = 0; mi < 8; ++mi)
#pragma unroll
    for (int ni = 0; ni < 4; ++ni) {
      int n = n0 + wc * 64 + ni * 16 + l16;
      float bias = dp_b[e * DMODEL + n];
#pragma unroll
      for (int rg = 0; rg < 4; ++rg) {
        int r = m0 + wr * 128 + mi * 16 + quad * 4 + rg;
        if (r < cnt) {
          float v = acc[mi][ni][rg] + bias;
          ybuf[(size_t)(offe + r) * DMODEL + n] = (__bf16)v;
        }
      }
    }
}

// ---------------- combine: out[t] = w0*y[slot0] + w1*y[slot1] ----------------
__global__ __launch_bounds__(256) void combine_kernel(
    const __bf16* __restrict__ ybuf, const int2* __restrict__ tok_slots,
    const float2* __restrict__ topk_w, float* __restrict__ out)
{
  int tid = threadIdx.x;
  int t = blockIdx.x * 2 + (tid >> 7);
  int d = (tid & 127) * 8;
  int2 sl = tok_slots[t];
  float2 w = topk_w[t];
  bf16_8 y0 = *(const bf16_8*)(ybuf + (size_t)sl.x * DMODEL + d);
  bf16_8 y1 = *(const bf16_8*)(ybuf + (size_t)sl.y * DMODEL + d);
  float* o = out + (size_t)t * DMODEL + d;
  f32_4 r0, r1;
#pragma unroll
  for (int i = 0; i < 4; ++i) r0[i] = w.x * (float)y0[i] + w.y * (float)y1[i];
#pragma unroll
  for (int i = 0; i < 4; ++i) r1[i] = w.x * (float)y0[4 + i] + w.y * (float)y1[4 + i];
  *(f32_4*)o = r0;
  *(f32_4*)(o + 4) = r1;
}

extern "C" void kernel_launch(void* const* d_in, const int* in_sizes, int n_in,
                              void* d_out, int out_size, void* d_ws, size_t ws_size,
                              hipStream_t stream)
{
  const float* x      = (const float*)d_in[0];
  const float* gate_w = (const float*)d_in[1];
  const float* gate_b = (const float*)d_in[2];
  const float* gp_w   = (const float*)d_in[3];
  const float* gp_b   = (const float*)d_in[4];
  const float* up_w   = (const float*)d_in[5];
  const float* up_b   = (const float*)d_in[6];
  const float* dp_w   = (const float*)d_in[7];
  const float* dp_b   = (const float*)d_in[8];

  // Workspace layout — ~118 MB. ybuf (67.1 MB) aliases xb+wb1 exactly (both dead after ffn1).
  char* ws = (char*)d_ws;
  size_t o = 0;
  __bf16* xb  = (__bf16*)(ws + o); o += (size_t)T_TOK * DMODEL * 2;          // 33.55 MB
  __bf16* wb1 = (__bf16*)(ws + o); o += (size_t)NEXP * 1024 * DMODEL * 2;    // 33.55 MB (g/u interleaved)
  __bf16* dpb = (__bf16*)(ws + o); o += (size_t)NEXP * DMODEL * HID * 2;     // 16.78 MB
  __bf16* hbuf = (__bf16*)(ws + o); o += (size_t)NASSIGN * HID * 2;          // 33.55 MB
  int*   tok_list = (int*)(ws + o); o += (size_t)NASSIGN * 4;                // 128 KB
  int2*  tok_slots = (int2*)(ws + o); o += (size_t)T_TOK * 8;                // 128 KB
  int*   topk_idx = (int*)(ws + o); o += (size_t)T_TOK * 4;                  // 64 KB
  float2* topk_w  = (float2*)(ws + o); o += (size_t)T_TOK * 8;               // 128 KB
  int*   block_hist = (int*)(ws + o); o += (size_t)HIST_BLK * NEXP * 4;      // 4 KB
  int*   block_base = (int*)(ws + o); o += (size_t)HIST_BLK * NEXP * 4;      // 4 KB
  int*   counts   = (int*)(ws + o); o += 64;
  int*   offsets  = (int*)(ws + o); o += 128;
  int*   mb_tab   = (int*)(ws + o); o += 4 * 160;                            // m-block map
  int*   nmb      = (int*)(ws + o); o += 64;
  __bf16* ybuf = (__bf16*)ws;  // [NASSIGN][DMODEL] bf16 = 67.1 MB, aliases xb+wb1

  float* out = (float*)d_out;
  float* aux = out + (size_t)T_TOK * DMODEL;

  gate_compute_kernel<<<T_TOK / 32, 256, 0, stream>>>(x, gate_w, gate_b, xb, topk_idx, topk_w);
  hist_kernel<<<HIST_BLK, TOK_PER_BLK, 0, stream>>>(topk_idx, block_hist);
  scan2_kernel<<<1, 64, 0, stream>>>(block_hist, counts, offsets, block_base, mb_tab, nmb, aux);
  scatter_kernel<<<HIST_BLK, TOK_PER_BLK, 0, stream>>>(topk_idx, block_base, tok_list, tok_slots);
  transpose_w1_kernel<<<dim3(512 / 32, 1024 / 32, 2 * NEXP), dim3(32, 8), 0, stream>>>(gp_w, up_w, wb1);
  transpose_dp_kernel<<<dim3(1024 / 32, 512 / 32, NEXP), dim3(32, 8), 0, stream>>>(dp_w, dpb);
  ffn1_kernel<<<dim3(4, NMB_MAX, 1), 512, 0, stream>>>(xb, wb1, gp_b, up_b,
                                                       counts, offsets, tok_list, mb_tab, nmb, hbuf);
  ffn2_kernel<<<dim3(4, NMB_MAX, 1), 512, 0, stream>>>(hbuf, dpb, dp_b,
                                                       counts, offsets, mb_tab, nmb, ybuf);
  combine_kernel<<<T_TOK / 2, 256, 0, stream>>>(ybuf, tok_slots, topk_w, out);
}

// Round 12
// 457.828 us; speedup vs baseline: 1.0648x; 1.0648x over previous
//
#include <hip/hip_runtime.h>
#include <hip/hip_bf16.h>
#include <math.h>

#define T_TOK 16384
#define DMODEL 1024
#define HID 512
#define NEXP 16
#define NASSIGN (T_TOK * 2)             // total (token, expert) pairs
#define HIST_BLK 64                     // blocks in hist/scatter phase
#define TOK_PER_BLK (T_TOK / HIST_BLK)  // 256
#define NMB_MAX 143                     // max total m-blocks: 128 + 15 (rounding)

typedef __bf16 bf16_8 __attribute__((ext_vector_type(8)));
typedef __bf16 bf16_4 __attribute__((ext_vector_type(4)));
typedef float f32_4 __attribute__((ext_vector_type(4)));

// Async global->LDS, 16B per lane. HW dest = wave-uniform base + lane*16 (linear).
__device__ __forceinline__ void gload16(const __bf16* g, __bf16* l) {
  __builtin_amdgcn_global_load_lds(
      (const __attribute__((address_space(1))) void*)g,
      (__attribute__((address_space(3))) void*)l, 16, 0, 0);
}

// ---------------- gate compute v2: gw cached in LDS, 4-token batching, no atomics -------------
__global__ __launch_bounds__(256) void gate_compute_kernel(
    const float* __restrict__ x, const float* __restrict__ gw, const float* __restrict__ gb,
    __bf16* __restrict__ xb, int* __restrict__ topk_idx, float2* __restrict__ topk_w)
{
  __shared__ __align__(16) float gws[4 * 1024 * 4];   // 64 KB: [g][k] f32_4

  int tid = threadIdx.x;
#pragma unroll
  for (int i = 0; i < 16; ++i) {
    int c = i * 256 + tid;
    f32_4 v = ((const f32_4*)gw)[c];
    ((f32_4*)gws)[((c & 3) << 10) | (c >> 2)] = v;
  }
  __syncthreads();

  int wave = tid >> 6, lane = tid & 63;
  int tbase = blockIdx.x * 32 + wave * 8;

#pragma unroll 1
  for (int pass = 0; pass < 2; ++pass) {
    int t0 = tbase + pass * 4;
    const float* xr0 = x + (size_t)t0 * DMODEL;
    const float* xr1 = xr0 + DMODEL;
    const float* xr2 = xr1 + DMODEL;
    const float* xr3 = xr2 + DMODEL;
    __bf16* xw0 = xb + (size_t)t0 * DMODEL;
    __bf16* xw1 = xw0 + DMODEL;
    __bf16* xw2 = xw1 + DMODEL;
    __bf16* xw3 = xw2 + DMODEL;

    f32_4 acc0[4], acc1[4], acc2[4], acc3[4];
    {
      f32_4 z = {0.f, 0.f, 0.f, 0.f};
#pragma unroll
      for (int g = 0; g < 4; ++g) { acc0[g] = z; acc1[g] = z; acc2[g] = z; acc3[g] = z; }
    }

#pragma unroll
    for (int j = 0; j < 16; ++j) {
      int k = j * 64 + lane;
      float xv0 = xr0[k], xv1 = xr1[k], xv2 = xr2[k], xv3 = xr3[k];
      xw0[k] = (__bf16)xv0;
      xw1[k] = (__bf16)xv1;
      xw2[k] = (__bf16)xv2;
      xw3[k] = (__bf16)xv3;
      f32_4 w0 = ((const f32_4*)gws)[k];
      f32_4 w1 = ((const f32_4*)gws)[1024 + k];
      f32_4 w2 = ((const f32_4*)gws)[2048 + k];
      f32_4 w3 = ((const f32_4*)gws)[3072 + k];
      acc0[0] += xv0 * w0; acc0[1] += xv0 * w1; acc0[2] += xv0 * w2; acc0[3] += xv0 * w3;
      acc1[0] += xv1 * w0; acc1[1] += xv1 * w1; acc1[2] += xv1 * w2; acc1[3] += xv1 * w3;
      acc2[0] += xv2 * w0; acc2[1] += xv2 * w1; acc2[2] += xv2 * w2; acc2[3] += xv2 * w3;
      acc3[0] += xv3 * w0; acc3[1] += xv3 * w1; acc3[2] += xv3 * w2; acc3[3] += xv3 * w3;
    }

#pragma unroll
    for (int g = 0; g < 4; ++g)
#pragma unroll
      for (int w = 0; w < 4; ++w) {
        float v0 = acc0[g][w], v1 = acc1[g][w], v2 = acc2[g][w], v3 = acc3[g][w];
#pragma unroll
        for (int s = 32; s; s >>= 1) {
          v0 += __shfl_xor(v0, s, 64);
          v1 += __shfl_xor(v1, s, 64);
          v2 += __shfl_xor(v2, s, 64);
          v3 += __shfl_xor(v3, s, 64);
        }
        acc0[g][w] = v0; acc1[g][w] = v1; acc2[g][w] = v2; acc3[g][w] = v3;
      }

    int ti = lane & 3;
    float sc[16];
#pragma unroll
    for (int e = 0; e < 16; ++e) {
      int g = e >> 2, w = e & 3;
      float v = ti == 0 ? acc0[g][w] : ti == 1 ? acc1[g][w] : ti == 2 ? acc2[g][w] : acc3[g][w];
      sc[e] = v + gb[e];
    }
    float mx = -1e30f;
#pragma unroll
    for (int e = 0; e < 16; ++e) mx = fmaxf(mx, sc[e]);
    float Z = 0.f;
#pragma unroll
    for (int e = 0; e < 16; ++e) { sc[e] = expf(sc[e] - mx); Z += sc[e]; }
    int i0 = 0; float s0 = sc[0];
#pragma unroll
    for (int e = 1; e < 16; ++e) if (sc[e] > s0) { s0 = sc[e]; i0 = e; }
    int i1 = -1; float s1 = -1e30f;
#pragma unroll
    for (int e = 0; e < 16; ++e) if (e != i0 && sc[e] > s1) { s1 = sc[e]; i1 = e; }
    s0 /= Z; s1 /= Z;
    float dn = s0 + s1 + 1e-9f;
    if (lane < 4) {
      int t = t0 + ti;
      topk_idx[t] = i0 | (i1 << 8);
      topk_w[t] = make_float2(s0 / dn, s1 / dn);
    }
  }
}

// ---------------- per-block expert histogram (LDS atomics only) ----------------
__global__ __launch_bounds__(256) void hist_kernel(
    const int* __restrict__ topk_idx, int* __restrict__ block_hist)
{
  __shared__ int cnt[NEXP];
  int tid = threadIdx.x;
  if (tid < NEXP) cnt[tid] = 0;
  __syncthreads();
  int t = blockIdx.x * TOK_PER_BLK + tid;
  int p = topk_idx[t];
  atomicAdd(&cnt[p & 0xff], 1);
  atomicAdd(&cnt[p >> 8], 1);
  __syncthreads();
  if (tid < NEXP) block_hist[blockIdx.x * NEXP + tid] = cnt[tid];
}

// ---------------- scan: counts, offsets, block bases, aux loss, m-block map ----------------
__global__ void scan2_kernel(const int* __restrict__ block_hist,
                             int* __restrict__ counts, int* __restrict__ offsets,
                             int* __restrict__ block_base, int* __restrict__ mb_tab,
                             int* __restrict__ nmb, float* __restrict__ aux_out)
{
  __shared__ int cl[NEXP];
  int lane = threadIdx.x;
  if (lane < NEXP) {
    int s = 0;
    for (int b = 0; b < HIST_BLK; ++b) s += block_hist[b * NEXP + lane];
    cl[lane] = s;
    counts[lane] = s;
  }
  __syncthreads();
  if (lane < NEXP) {
    int off = 0;
    for (int e = 0; e < lane; ++e) off += cl[e];
    offsets[lane] = off;
    int base = off;
    for (int b = 0; b < HIST_BLK; ++b) {
      block_base[b * NEXP + lane] = base;
      base += block_hist[b * NEXP + lane];
    }
  }
  if (lane == 0) {
    int tot = 0; float pen = 0.f;
    const float cap = 1.25f * (float)(T_TOK * 2) / (float)NEXP; // 2560
    for (int e = 0; e < NEXP; ++e) {
      tot += cl[e];
      float ld = (float)cl[e] - cap;
      pen += ld > 0.f ? ld : 0.f;
    }
    offsets[NEXP] = tot;
    aux_out[0] = 0.01f * pen / (float)NEXP / (float)T_TOK;
    // m-block map: flat list of (expert<<8 | mblock) for all non-empty tiles
    int idx = 0;
    for (int e = 0; e < NEXP; ++e) {
      int nb = (cl[e] + 255) >> 8;
      for (int b = 0; b < nb; ++b) mb_tab[idx++] = (e << 8) | b;
    }
    nmb[0] = idx;
  }
}

// ---------------- scatter: compact-list positions + inverse map (token -> slots) ----------------
__global__ __launch_bounds__(256) void scatter_kernel(
    const int* __restrict__ topk_idx, const int* __restrict__ block_base,
    int* __restrict__ tok_list, int2* __restrict__ tok_slots)
{
  __shared__ int base[NEXP];
  int tid = threadIdx.x;
  if (tid < NEXP) base[tid] = block_base[blockIdx.x * NEXP + tid];
  __syncthreads();
  int t = blockIdx.x * TOK_PER_BLK + tid;
  int p = topk_idx[t];
  int i0 = p & 0xff, i1 = p >> 8;
  int p0 = atomicAdd(&base[i0], 1);
  tok_list[p0] = t;
  int p1 = atomicAdd(&base[i1], 1);
  tok_list[p1] = t;
  tok_slots[t] = make_int2(p0, p1);
}

// ---------------- transpose gp/up fp32[E][1024][512] -> interleaved bf16 wb1[E][n'][1024]
__global__ __launch_bounds__(256) void transpose_w1_kernel(const float* __restrict__ gp,
                                                           const float* __restrict__ up,
                                                           __bf16* __restrict__ wb1)
{
  __shared__ float tile[32][33];
  int ez = blockIdx.z;
  int e = ez >> 1, isup = ez & 1;
  const float* in = isup ? up : gp;
  int c0 = blockIdx.x * 32, r0 = blockIdx.y * 32;
  const float* src = in + ((size_t)e * 1024 + r0) * 512 + c0;
#pragma unroll
  for (int i = 0; i < 4; ++i) {
    int r = threadIdx.y + i * 8;
    tile[r][threadIdx.x] = src[(size_t)r * 512 + threadIdx.x];
  }
  __syncthreads();
#pragma unroll
  for (int i = 0; i < 4; ++i) {
    int cc = threadIdx.y + i * 8;
    int np = 2 * c0 + 2 * (cc & ~15) + (cc & 15) + 16 * isup;
    wb1[((size_t)e * 1024 + np) * 1024 + r0 + threadIdx.x] = (__bf16)tile[threadIdx.x][cc];
  }
}

// ---------------- transpose dp fp32[E][512][1024] -> bf16 dpb[E][1024][512] ----------------
__global__ __launch_bounds__(256) void transpose_dp_kernel(const float* __restrict__ in,
                                                           __bf16* __restrict__ out)
{
  __shared__ float tile[32][33];
  int e = blockIdx.z;
  int c0 = blockIdx.x * 32, r0 = blockIdx.y * 32;
  const float* src = in + ((size_t)e * 512 + r0) * 1024 + c0;
#pragma unroll
  for (int i = 0; i < 4; ++i) {
    int r = threadIdx.y + i * 8;
    tile[r][threadIdx.x] = src[(size_t)r * 1024 + threadIdx.x];
  }
  __syncthreads();
  __bf16* dst = out + ((size_t)e * 1024 + c0) * 512 + r0;
#pragma unroll
  for (int i = 0; i < 4; ++i) {
    int c = threadIdx.y + i * 8;
    dst[(size_t)c * 512 + threadIdx.x] = (__bf16)tile[threadIdx.x][c];
  }
}

// ==================== 8-wave 256x256xBK64 grouped-GEMM, m230-V0 cadence =====================
// R11 post-mortem: ffn1 pinned at 135-143us / MfmaUtil ~20% across THREE different pipelines;
// the invariant was 8 raw barriers + lgkmcnt rejoins per 64-K. Reference m230-V0 (2-phase,
// ONE __syncthreads per 64-K tile) = 655-682 TF vs our 494-509. This version is the proven
// cadence: per K-tile {STAGE(next) -> ds_read 24 b128 (compiler-scheduled counted lgkmcnt)
// -> 64 MFMA setprio-wrapped -> __syncthreads (full drain)}. 16 barriers total (ffn1).
// Swizzle: R6's verified-zero-conflict BK64 XOR (slot = chunk ^ (row&7) both sides).
// Grid: R10's proven block-map (572 blocks, FETCH 146->70 MB) + T1 bijective XCD swizzle.

#define MF(mi, ni, a, b) acc[mi][ni] = __builtin_amdgcn_mfma_f32_16x16x32_bf16(a, b, acc[mi][ni], 0, 0, 0)

#define STAGE_T(b, kt) {                                             \
    gload16(ga0 + (kt) * 64, lds + (b) * 32768 + tid * 8);           \
    gload16(ga1 + (kt) * 64, lds + (b) * 32768 + 4096 + tid * 8);    \
    gload16(ga2 + (kt) * 64, lds + (b) * 32768 + 8192 + tid * 8);    \
    gload16(ga3 + (kt) * 64, lds + (b) * 32768 + 12288 + tid * 8);   \
    gload16(gb0 + (kt) * 64, lds + (b) * 32768 + 16384 + tid * 8);   \
    gload16(gb1 + (kt) * 64, lds + (b) * 32768 + 20480 + tid * 8);   \
    gload16(gb2 + (kt) * 64, lds + (b) * 32768 + 24576 + tid * 8);   \
    gload16(gb3 + (kt) * 64, lds + (b) * 32768 + 28672 + tid * 8); }

#define GTILE(ktv, STG)                                                           \
  {                                                                               \
    const __bf16* A_ = lds + ((ktv) & 1) * 32768;                                 \
    const __bf16* B_ = A_ + 16384;                                                \
    if (STG) STAGE_T(((ktv) + 1) & 1, (ktv) + 1);                                 \
    bf16_8 af[8], bf[4];                                                          \
    _Pragma("unroll")                                                             \
    for (int mi = 0; mi < 8; ++mi)                                                \
      af[mi] = *(const bf16_8*)(A_ + abase + mi * 1024 + c0);                     \
    _Pragma("unroll")                                                             \
    for (int ni = 0; ni < 4; ++ni)                                                \
      bf[ni] = *(const bf16_8*)(B_ + bbase + ni * 1024 + c0);                     \
    __builtin_amdgcn_s_setprio(1);                                                \
    _Pragma("unroll")                                                             \
    for (int mi = 0; mi < 8; ++mi) {                                              \
      MF(mi, 0, af[mi], bf[0]); MF(mi, 1, af[mi], bf[1]);                         \
      MF(mi, 2, af[mi], bf[2]); MF(mi, 3, af[mi], bf[3]);                         \
    }                                                                             \
    _Pragma("unroll")                                                             \
    for (int mi = 0; mi < 8; ++mi)                                                \
      af[mi] = *(const bf16_8*)(A_ + abase + mi * 1024 + (c0 ^ 32));              \
    _Pragma("unroll")                                                             \
    for (int ni = 0; ni < 4; ++ni)                                                \
      bf[ni] = *(const bf16_8*)(B_ + bbase + ni * 1024 + (c0 ^ 32));              \
    _Pragma("unroll")                                                             \
    for (int mi = 0; mi < 8; ++mi) {                                              \
      MF(mi, 0, af[mi], bf[0]); MF(mi, 1, af[mi], bf[1]);                         \
      MF(mi, 2, af[mi], bf[2]); MF(mi, 3, af[mi], bf[3]);                         \
    }                                                                             \
    __builtin_amdgcn_s_setprio(0);                                                \
    __syncthreads();                                                              \
  }

template<int KTILES>
__device__ __forceinline__ void gemm8w(
    const __bf16* ga0, const __bf16* ga1, const __bf16* ga2, const __bf16* ga3,
    const __bf16* gb0, const __bf16* gb1, const __bf16* gb2, const __bf16* gb3,
    __bf16* lds, f32_4 (&acc)[8][4])
{
  const int tid = threadIdx.x;
  const int wid = tid >> 6, wr = wid >> 2, wc = wid & 3;
  const int lane = tid & 63, quad = lane >> 4, l16 = lane & 15;
  const int c0 = (quad ^ (l16 & 7)) * 8;   // ks0 swizzled chunk offset (elements); ks1 = c0^32
  const int abase = (wr * 128 + l16) * 64;
  const int bbase = (wc * 64 + l16) * 64;

  STAGE_T(0, 0);
  __syncthreads();

#pragma unroll 1
  for (int kt = 0; kt < KTILES - 1; ++kt) {
    GTILE(kt, 1);
  }
  GTILE(KTILES - 1, 0);
}

// -------- FFN1: h = (x@gp + b) * silu(x@up + b), B = interleaved wb1, A gathered --------
__global__ __launch_bounds__(512, 2) void ffn1_kernel(
    const __bf16* __restrict__ xb, const __bf16* __restrict__ wb1,
    const float* __restrict__ gp_b, const float* __restrict__ up_b,
    const int* __restrict__ counts, const int* __restrict__ offsets,
    const int* __restrict__ tok_list, const int* __restrict__ mb_tab,
    const int* __restrict__ nmb, __bf16* __restrict__ h)
{
  __shared__ __align__(16) __bf16 lds[2 * 32768];   // 128 KB: 2 x (A 32KB + B 32KB)
  __shared__ int toks[256];

  // T1: bijective XCD swizzle over nwg = 4*143 = 572 (q=71, r=4).
  int lin = blockIdx.y * 4 + blockIdx.x;
  int xcd = lin & 7, sub = lin >> 3;
  int wg = (xcd < 4 ? xcd * 72 : 288 + (xcd - 4) * 71) + sub;
  int y = wg >> 2, xn = wg & 3;
  if (y >= nmb[0]) return;
  int me = mb_tab[y];
  int e = me >> 8;
  int m0 = (me & 255) << 8;
  int cnt = counts[e], offe = offsets[e];
  int n0 = xn * 256;   // n' base (interleaved g/u space)

  int tid = threadIdx.x;
  if (tid < 256) {
    int r = m0 + tid;
    toks[tid] = tok_list[offe + (r < cnt ? r : cnt - 1)];  // clamp: garbage rows never stored
  }
  __syncthreads();

  int rr = tid >> 3;                           // chunk row 0..63 (4 row-groups of 64)
  int ko = ((tid & 7) ^ (rr & 7)) * 8;         // swizzled source chunk (constant per thread)

  const __bf16* ga0 = xb + (size_t)toks[rr] * DMODEL + ko;
  const __bf16* ga1 = xb + (size_t)toks[64 + rr] * DMODEL + ko;
  const __bf16* ga2 = xb + (size_t)toks[128 + rr] * DMODEL + ko;
  const __bf16* ga3 = xb + (size_t)toks[192 + rr] * DMODEL + ko;
  const __bf16* gb0 = wb1 + ((size_t)e * 1024 + n0 + rr) * DMODEL + ko;
  const __bf16* gb1 = wb1 + ((size_t)e * 1024 + n0 + 64 + rr) * DMODEL + ko;
  const __bf16* gb2 = wb1 + ((size_t)e * 1024 + n0 + 128 + rr) * DMODEL + ko;
  const __bf16* gb3 = wb1 + ((size_t)e * 1024 + n0 + 192 + rr) * DMODEL + ko;

  f32_4 acc[8][4];
  {
    f32_4 z = {0.f, 0.f, 0.f, 0.f};
#pragma unroll
    for (int a = 0; a < 8; ++a)
#pragma unroll
      for (int b = 0; b < 4; ++b) acc[a][b] = z;
  }

  gemm8w<DMODEL / 64>(ga0, ga1, ga2, ga3, gb0, gb1, gb2, gb3, lds, acc);

  int wid = tid >> 6, wr = wid >> 2, wc = wid & 3;
  int lane = tid & 63, quad = lane >> 4, l16 = lane & 15;

  // Epilogue: pair n'-frags (2j, 2j+1) = (g, u); h col c = n0/2 + wc*32 + j*16 + l16.
#pragma unroll
  for (int mi = 0; mi < 8; ++mi)
#pragma unroll
    for (int j = 0; j < 2; ++j) {
      int c = (n0 >> 1) + wc * 32 + j * 16 + l16;
      float gbias = gp_b[e * HID + c];
      float ubias = up_b[e * HID + c];
#pragma unroll
      for (int rg = 0; rg < 4; ++rg) {
        int r = m0 + wr * 128 + mi * 16 + quad * 4 + rg;  // C/D: col=lane&15, row=quad*4+reg
        if (r < cnt) {
          float g = acc[mi][2 * j][rg] + gbias;
          float u = acc[mi][2 * j + 1][rg] + ubias;
          float sw = u / (1.f + expf(-u));
          h[(size_t)(offe + r) * HID + c] = (__bf16)(g * sw);
        }
      }
    }
}

// -------- FFN2: ybuf[slot] = h[slot] @ dp + b (contiguous A, coalesced stores, NO atomics) ----
__global__ __launch_bounds__(512, 2) void ffn2_kernel(
    const __bf16* __restrict__ h, const __bf16* __restrict__ dpb, const float* __restrict__ dp_b,
    const int* __restrict__ counts, const int* __restrict__ offsets,
    const int* __restrict__ mb_tab, const int* __restrict__ nmb,
    __bf16* __restrict__ ybuf)
{
  __shared__ __align__(16) __bf16 lds[2 * 32768];   // 128 KB

  int lin = blockIdx.y * 4 + blockIdx.x;
  int xcd = lin & 7, sub = lin >> 3;
  int wg = (xcd < 4 ? xcd * 72 : 288 + (xcd - 4) * 71) + sub;
  int y = wg >> 2, xn = wg & 3;
  if (y >= nmb[0]) return;
  int me = mb_tab[y];
  int e = me >> 8;
  int m0 = (me & 255) << 8;
  int cnt = counts[e], offe = offsets[e];
  int n0 = xn * 256;

  int tid = threadIdx.x;
  int rr = tid >> 3;
  int ko = ((tid & 7) ^ (rr & 7)) * 8;

  int ra0 = m0 + rr;        if (ra0 >= cnt) ra0 = cnt - 1;   // clamp: garbage rows never stored
  int ra1 = m0 + 64 + rr;   if (ra1 >= cnt) ra1 = cnt - 1;
  int ra2 = m0 + 128 + rr;  if (ra2 >= cnt) ra2 = cnt - 1;
  int ra3 = m0 + 192 + rr;  if (ra3 >= cnt) ra3 = cnt - 1;
  const __bf16* ga0 = h + (size_t)(offe + ra0) * HID + ko;
  const __bf16* ga1 = h + (size_t)(offe + ra1) * HID + ko;
  const __bf16* ga2 = h + (size_t)(offe + ra2) * HID + ko;
  const __bf16* ga3 = h + (size_t)(offe + ra3) * HID + ko;
  const __bf16* gb0 = dpb + ((size_t)e * DMODEL + n0 + rr) * HID + ko;
  const __bf16* gb1 = dpb + ((size_t)e * DMODEL + n0 + 64 + rr) * HID + ko;
  const __bf16* gb2 = dpb + ((size_t)e * DMODEL + n0 + 128 + rr) * HID + ko;
  const __bf16* gb3 = dpb + ((size_t)e * DMODEL + n0 + 192 + rr) * HID + ko;

  f32_4 acc[8][4];
  {
    f32_4 z = {0.f, 0.f, 0.f, 0.f};
#pragma unroll
    for (int a = 0; a < 8; ++a)
#pragma unroll
      for (int b = 0; b < 4; ++b) acc[a][b] = z;
  }

  gemm8w<HID / 64>(ga0, ga1, ga2, ga3, gb0, gb1, gb2, gb3, lds, acc);

  int wid = tid >> 6, wr = wid >> 2, wc = wid & 3;
  int lane = tid & 63, quad = lane >> 4, l16 = lane & 15;

#pragma unroll
  for (int mi = 0; mi < 8; ++mi)
#pragma unroll
    for (int ni = 0; ni < 4; ++ni) {
      int n = n0 + wc * 64 + ni * 16 + l16;
      float bias = dp_b[e * DMODEL + n];
#pragma unroll
      for (int rg = 0; rg < 4; ++rg) {
        int r = m0 + wr * 128 + mi * 16 + quad * 4 + rg;
        if (r < cnt) {
          float v = acc[mi][ni][rg] + bias;
          ybuf[(size_t)(offe + r) * DMODEL + n] = (__bf16)v;
        }
      }
    }
}

// ---------------- combine: out[t] = w0*y[slot0] + w1*y[slot1] ----------------
__global__ __launch_bounds__(256) void combine_kernel(
    const __bf16* __restrict__ ybuf, const int2* __restrict__ tok_slots,
    const float2* __restrict__ topk_w, float* __restrict__ out)
{
  int tid = threadIdx.x;
  int t = blockIdx.x * 2 + (tid >> 7);
  int d = (tid & 127) * 8;
  int2 sl = tok_slots[t];
  float2 w = topk_w[t];
  bf16_8 y0 = *(const bf16_8*)(ybuf + (size_t)sl.x * DMODEL + d);
  bf16_8 y1 = *(const bf16_8*)(ybuf + (size_t)sl.y * DMODEL + d);
  float* o = out + (size_t)t * DMODEL + d;
  f32_4 r0, r1;
#pragma unroll
  for (int i = 0; i < 4; ++i) r0[i] = w.x * (float)y0[i] + w.y * (float)y1[i];
#pragma unroll
  for (int i = 0; i < 4; ++i) r1[i] = w.x * (float)y0[4 + i] + w.y * (float)y1[4 + i];
  *(f32_4*)o = r0;
  *(f32_4*)(o + 4) = r1;
}

extern "C" void kernel_launch(void* const* d_in, const int* in_sizes, int n_in,
                              void* d_out, int out_size, void* d_ws, size_t ws_size,
                              hipStream_t stream)
{
  const float* x      = (const float*)d_in[0];
  const float* gate_w = (const float*)d_in[1];
  const float* gate_b = (const float*)d_in[2];
  const float* gp_w   = (const float*)d_in[3];
  const float* gp_b   = (const float*)d_in[4];
  const float* up_w   = (const float*)d_in[5];
  const float* up_b   = (const float*)d_in[6];
  const float* dp_w   = (const float*)d_in[7];
  const float* dp_b   = (const float*)d_in[8];

  // Workspace layout — ~118 MB. ybuf (67.1 MB) aliases xb+wb1 exactly (both dead after ffn1).
  char* ws = (char*)d_ws;
  size_t o = 0;
  __bf16* xb  = (__bf16*)(ws + o); o += (size_t)T_TOK * DMODEL * 2;          // 33.55 MB
  __bf16* wb1 = (__bf16*)(ws + o); o += (size_t)NEXP * 1024 * DMODEL * 2;    // 33.55 MB (g/u interleaved)
  __bf16* dpb = (__bf16*)(ws + o); o += (size_t)NEXP * DMODEL * HID * 2;     // 16.78 MB
  __bf16* hbuf = (__bf16*)(ws + o); o += (size_t)NASSIGN * HID * 2;          // 33.55 MB
  int*   tok_list = (int*)(ws + o); o += (size_t)NASSIGN * 4;                // 128 KB
  int2*  tok_slots = (int2*)(ws + o); o += (size_t)T_TOK * 8;                // 128 KB
  int*   topk_idx = (int*)(ws + o); o += (size_t)T_TOK * 4;                  // 64 KB
  float2* topk_w  = (float2*)(ws + o); o += (size_t)T_TOK * 8;               // 128 KB
  int*   block_hist = (int*)(ws + o); o += (size_t)HIST_BLK * NEXP * 4;      // 4 KB
  int*   block_base = (int*)(ws + o); o += (size_t)HIST_BLK * NEXP * 4;      // 4 KB
  int*   counts   = (int*)(ws + o); o += 64;
  int*   offsets  = (int*)(ws + o); o += 128;
  int*   mb_tab   = (int*)(ws + o); o += 4 * 160;                            // m-block map
  int*   nmb      = (int*)(ws + o); o += 64;
  __bf16* ybuf = (__bf16*)ws;  // [NASSIGN][DMODEL] bf16 = 67.1 MB, aliases xb+wb1

  float* out = (float*)d_out;
  float* aux = out + (size_t)T_TOK * DMODEL;

  gate_compute_kernel<<<T_TOK / 32, 256, 0, stream>>>(x, gate_w, gate_b, xb, topk_idx, topk_w);
  hist_kernel<<<HIST_BLK, TOK_PER_BLK, 0, stream>>>(topk_idx, block_hist);
  scan2_kernel<<<1, 64, 0, stream>>>(block_hist, counts, offsets, block_base, mb_tab, nmb, aux);
  scatter_kernel<<<HIST_BLK, TOK_PER_BLK, 0, stream>>>(topk_idx, block_base, tok_list, tok_slots);
  transpose_w1_kernel<<<dim3(512 / 32, 1024 / 32, 2 * NEXP), dim3(32, 8), 0, stream>>>(gp_w, up_w, wb1);
  transpose_dp_kernel<<<dim3(1024 / 32, 512 / 32, NEXP), dim3(32, 8), 0, stream>>>(dp_w, dpb);
  ffn1_kernel<<<dim3(4, NMB_MAX, 1), 512, 0, stream>>>(xb, wb1, gp_b, up_b,
                                                       counts, offsets, tok_list, mb_tab, nmb, hbuf);
  ffn2_kernel<<<dim3(4, NMB_MAX, 1), 512, 0, stream>>>(hbuf, dpb, dp_b,
                                                       counts, offsets, mb_tab, nmb, ybuf);
  combine_kernel<<<T_TOK / 2, 256, 0, stream>>>(ybuf, tok_slots, topk_w, out);
}